// Round 8
// baseline (57.501 us; speedup 1.0000x reference)
//
#include <hip/hip_runtime.h>
#include <math.h>

#define BB 32
#define SS 2048
#define DD 1024
#define NCH 32      // S-chunks (blocks) per b
#define CHS 64      // rows per chunk

typedef float f4 __attribute__((ext_vector_type(4)));   // nt-load-compatible

// ws layout (floats):
//   energy : BB*SS          (256 KiB)
//   partial: BB*NCH*DD      (4 MiB)
//   ml     : BB*NCH*2       (8 KiB)

// K1: fused energy + online-softmax PV — the proven R2 structure.
// One block per (b, 64-row chunk); thread owns one float4 of D.
// 1-row prefetch; one barrier per row; nontemporal loads on the enc stream.
__global__ __launch_bounds__(256) void fused_pass(const float* __restrict__ q,
                                                  const float* __restrict__ enc,
                                                  float* __restrict__ energy,
                                                  float* __restrict__ partial,
                                                  float* __restrict__ ml) {
    int blk = blockIdx.x;             // b*NCH + cb
    int b   = blk >> 5;
    int cb  = blk & (NCH - 1);
    int tid = threadIdx.x;
    int wid = tid >> 6;
    int ln  = tid & 63;

    __shared__ float red[2][4];

    f4 qv = ((const f4*)(q + (size_t)b * DD))[tid];

    int s0 = cb * CHS;
    const f4* base = (const f4*)enc;
    const size_t rs = (size_t)BB * (DD / 4);            // f4 per s step
    size_t idx = (size_t)(s0 * BB + b) * (DD / 4) + tid;

    float m = -1e30f, l = 0.f;
    f4 acc = {0.f, 0.f, 0.f, 0.f};
    f4 v = __builtin_nontemporal_load(base + idx);

    for (int i = 0; i < CHS; ++i) {
        f4 vn = {0.f, 0.f, 0.f, 0.f};
        if (i + 1 < CHS)
            vn = __builtin_nontemporal_load(base + idx + (size_t)(i + 1) * rs);

        float pd = v.x * qv.x + v.y * qv.y + v.z * qv.z + v.w * qv.w;
#pragma unroll
        for (int off = 32; off > 0; off >>= 1)
            pd += __shfl_xor(pd, off, 64);
        if (ln == 0) red[i & 1][wid] = pd;
        __syncthreads();
        float e = red[i & 1][0] + red[i & 1][1] + red[i & 1][2] + red[i & 1][3];

        if (tid == 0) energy[b * SS + s0 + i] = e;

        float mn    = fmaxf(m, e);
        float scale = __expf(m - mn);
        float p     = __expf(e - mn);
        l = l * scale + p;
        acc.x = acc.x * scale + p * v.x;
        acc.y = acc.y * scale + p * v.y;
        acc.z = acc.z * scale + p * v.z;
        acc.w = acc.w * scale + p * v.w;
        m = mn;
        v = vn;
    }

    ((f4*)(partial + (size_t)blk * DD))[tid] = acc;
    if (tid == 0) { ml[blk * 2] = m; ml[blk * 2 + 1] = l; }
}

// K2: merge NCH chunk partials per b -> values; write scores.
// Grid = BB*8: block owns D/8 of values and S/8 of scores.
__global__ __launch_bounds__(256) void merge_scores(const float* __restrict__ partial,
                                                    const float* __restrict__ ml,
                                                    const float* __restrict__ energy,
                                                    float* __restrict__ values,
                                                    float* __restrict__ scores) {
    int blk = blockIdx.x;
    int b   = blk >> 3;
    int oct = blk & 7;
    int tid = threadIdx.x;
    __shared__ float sm[NCH], sl[NCH], sw[NCH];

    if (tid < NCH) {
        sm[tid] = ml[(b * NCH + tid) * 2];
        sl[tid] = ml[(b * NCH + tid) * 2 + 1];
    }
    __syncthreads();

    float M = -1e30f;
#pragma unroll
    for (int c = 0; c < NCH; ++c) M = fmaxf(M, sm[c]);
    if (tid < NCH) sw[tid] = __expf(sm[tid] - M);
    __syncthreads();

    float L = 0.f;
#pragma unroll
    for (int c = 0; c < NCH; ++c) L += sw[c] * sl[c];
    float inv = 1.f / L;

    if (tid < 128) {
        int d = oct * 128 + tid;
        float acc = 0.f;
#pragma unroll
        for (int c = 0; c < NCH; ++c)
            acc += sw[c] * partial[(size_t)(b * NCH + c) * DD + d];
        values[b * DD + d] = acc * inv;
    }

    int sidx = b * SS + oct * 256 + tid;
    scores[sidx] = __expf(energy[sidx] - M) * inv;
}

extern "C" void kernel_launch(void* const* d_in, const int* in_sizes, int n_in,
                              void* d_out, int out_size, void* d_ws, size_t ws_size,
                              hipStream_t stream) {
    const float* q   = (const float*)d_in[0];   // (1,B,D)
    const float* enc = (const float*)d_in[1];   // (S,B,D)
    float* out    = (float*)d_out;
    float* values = out;                        // (B,D)
    float* scores = out + BB * DD;              // (B,S)

    float* energy  = (float*)d_ws;                         // BB*SS
    float* partial = energy + BB * SS;                     // BB*NCH*DD
    float* ml      = partial + (size_t)BB * NCH * DD;      // BB*NCH*2

    fused_pass<<<BB * NCH, 256, 0, stream>>>(q, enc, energy, partial, ml);
    merge_scores<<<BB * 8, 256, 0, stream>>>(partial, ml, energy, values, scores);
}

// Round 9
// 50.806 us; speedup vs baseline: 1.1318x; 1.1318x over previous
//
#include <hip/hip_runtime.h>
#include <math.h>

#define BB 32
#define SS 2048
#define DD 1024
#define NCH 32      // S-chunks (blocks) per b
#define CHS 64      // rows per chunk

// ws layout (floats):
//   energy : BB*SS          (256 KiB)
//   partial: BB*NCH*DD      (4 MiB)
//   ml     : BB*NCH*2       (8 KiB)

// K1: fused energy + online-softmax PV — exact R2 structure (proven 53.8 us
// total). One block per (b, 64-row chunk); thread owns one float4 of D.
// 1-row prefetch; one barrier per row (double-buffered LDS reduce).
__global__ __launch_bounds__(256) void fused_pass(const float* __restrict__ q,
                                                  const float* __restrict__ enc,
                                                  float* __restrict__ energy,
                                                  float* __restrict__ partial,
                                                  float* __restrict__ ml) {
    int blk = blockIdx.x;             // b*NCH + cb
    int b   = blk >> 5;
    int cb  = blk & (NCH - 1);
    int tid = threadIdx.x;
    int wid = tid >> 6;
    int ln  = tid & 63;

    __shared__ float red[2][4];

    float4 qv = ((const float4*)(q + (size_t)b * DD))[tid];

    int s0 = cb * CHS;
    const float4* base = (const float4*)enc;
    const size_t rs = (size_t)BB * (DD / 4);            // float4 per s step
    size_t idx = (size_t)(s0 * BB + b) * (DD / 4) + tid;

    float m = -1e30f, l = 0.f;
    float4 acc = {0.f, 0.f, 0.f, 0.f};
    float4 v = base[idx];

    for (int i = 0; i < CHS; ++i) {
        float4 vn = {0.f, 0.f, 0.f, 0.f};
        if (i + 1 < CHS) vn = base[idx + (size_t)(i + 1) * rs];  // prefetch

        float pd = v.x * qv.x + v.y * qv.y + v.z * qv.z + v.w * qv.w;
#pragma unroll
        for (int off = 32; off > 0; off >>= 1)
            pd += __shfl_xor(pd, off, 64);
        if (ln == 0) red[i & 1][wid] = pd;
        __syncthreads();
        float e = red[i & 1][0] + red[i & 1][1] + red[i & 1][2] + red[i & 1][3];

        if (tid == 0) energy[b * SS + s0 + i] = e;

        float mn    = fmaxf(m, e);
        float scale = __expf(m - mn);
        float p     = __expf(e - mn);
        l = l * scale + p;
        acc.x = acc.x * scale + p * v.x;
        acc.y = acc.y * scale + p * v.y;
        acc.z = acc.z * scale + p * v.z;
        acc.w = acc.w * scale + p * v.w;
        m = mn;
        v = vn;
    }

    ((float4*)(partial + (size_t)blk * DD))[tid] = acc;
    if (tid == 0) { ml[blk * 2] = m; ml[blk * 2 + 1] = l; }
}

// K2: merge NCH chunk partials per b -> values; write scores.
// Grid = BB*8: block owns D/8 of values and S/8 of scores.
__global__ __launch_bounds__(256) void merge_scores(const float* __restrict__ partial,
                                                    const float* __restrict__ ml,
                                                    const float* __restrict__ energy,
                                                    float* __restrict__ values,
                                                    float* __restrict__ scores) {
    int blk = blockIdx.x;
    int b   = blk >> 3;
    int oct = blk & 7;
    int tid = threadIdx.x;
    __shared__ float sm[NCH], sl[NCH], sw[NCH];

    if (tid < NCH) {
        sm[tid] = ml[(b * NCH + tid) * 2];
        sl[tid] = ml[(b * NCH + tid) * 2 + 1];
    }
    __syncthreads();

    float M = -1e30f;
#pragma unroll
    for (int c = 0; c < NCH; ++c) M = fmaxf(M, sm[c]);
    if (tid < NCH) sw[tid] = __expf(sm[tid] - M);
    __syncthreads();

    float L = 0.f;
#pragma unroll
    for (int c = 0; c < NCH; ++c) L += sw[c] * sl[c];
    float inv = 1.f / L;

    if (tid < 128) {
        int d = oct * 128 + tid;
        float acc = 0.f;
#pragma unroll
        for (int c = 0; c < NCH; ++c)
            acc += sw[c] * partial[(size_t)(b * NCH + c) * DD + d];
        values[b * DD + d] = acc * inv;
    }

    int sidx = b * SS + oct * 256 + tid;
    scores[sidx] = __expf(energy[sidx] - M) * inv;
}

extern "C" void kernel_launch(void* const* d_in, const int* in_sizes, int n_in,
                              void* d_out, int out_size, void* d_ws, size_t ws_size,
                              hipStream_t stream) {
    const float* q   = (const float*)d_in[0];   // (1,B,D)
    const float* enc = (const float*)d_in[1];   // (S,B,D)
    float* out    = (float*)d_out;
    float* values = out;                        // (B,D)
    float* scores = out + BB * DD;              // (B,S)

    float* energy  = (float*)d_ws;                         // BB*SS
    float* partial = energy + BB * SS;                     // BB*NCH*DD
    float* ml      = partial + (size_t)BB * NCH * DD;      // BB*NCH*2

    fused_pass<<<BB * NCH, 256, 0, stream>>>(q, enc, energy, partial, ml);
    merge_scores<<<BB * 8, 256, 0, stream>>>(partial, ml, energy, values, scores);
}